// Round 6
// baseline (281.032 us; speedup 1.0000x reference)
//
#include <hip/hip_runtime.h>
#include <hip/hip_bf16.h>
#include <math.h>

#define N 4096
#define D 1024
#define PANEL 128
#define NPANEL 32                         // N / PANEL
#define NTRI (NPANEL * (NPANEL + 1) / 2)  // 528 upper-triangle tiles
#define BK 32
#define NITER (D / BK)                    // 32 K-iters
#define PANBYTES 131072                   // one panel, one matrix: 32 kc * 4096 B

typedef float f32x4 __attribute__((ext_vector_type(4)));

// Blocked fp8 layout, per matrix (unchanged from round 5, verified correct):
//   off(row, kc, b) = ((row>>7)*32 + kc)*4096 + (row&127)*32 + b_phys
//   b_phys: 8B-group swizzle  b_phys = ((G ^ ((r>>2)&3))<<3) | (b&7),  G = b>>3

// ---------------- zero rowstats (N*3) ----------------
__global__ void zero_kernel(float* p) {
  int i = blockIdx.x * 256 + threadIdx.x;
  if (i < N * 3) p[i] = 0.0f;
}

// ---------------- prep: wave-per-row normalize -> blocked fp8, fused row-KL ----------------
__global__ __launch_bounds__(256) void prep_kernel(const float* __restrict__ tgt,
                                                   const float* __restrict__ prd,
                                                   uint8_t* __restrict__ tn,
                                                   uint8_t* __restrict__ pn,
                                                   float* __restrict__ rowkl) {
  const int wid = threadIdx.x >> 6, lane = threadIdx.x & 63;
  const int row = blockIdx.x * 4 + wid;
  const float* tr = tgt + (size_t)row * D;
  const float* pr = prd + (size_t)row * D;
  float4 tv[4], pv[4];
  #pragma unroll
  for (int j = 0; j < 4; j++) {
    tv[j] = ((const float4*)tr)[j * 64 + lane];
    pv[j] = ((const float4*)pr)[j * 64 + lane];
  }
  float ss_t = 0.f, ss_p = 0.f, mx_t = -1e30f, mx_p = -1e30f;
  #pragma unroll
  for (int j = 0; j < 4; j++) {
    float t_[4] = {tv[j].x, tv[j].y, tv[j].z, tv[j].w};
    float p_[4] = {pv[j].x, pv[j].y, pv[j].z, pv[j].w};
    #pragma unroll
    for (int k = 0; k < 4; k++) {
      ss_t += t_[k] * t_[k]; ss_p += p_[k] * p_[k];
      mx_t = fmaxf(mx_t, t_[k]); mx_p = fmaxf(mx_p, p_[k]);
    }
  }
  #pragma unroll
  for (int o = 32; o > 0; o >>= 1) {
    ss_t += __shfl_xor(ss_t, o);
    ss_p += __shfl_xor(ss_p, o);
    mx_t = fmaxf(mx_t, __shfl_xor(mx_t, o));
    mx_p = fmaxf(mx_p, __shfl_xor(mx_p, o));
  }
  float rnt = 1.0f / fmaxf(sqrtf(ss_t), 1e-8f);
  float rnp = 1.0f / fmaxf(sqrtf(ss_p), 1e-8f);

  const int P = row >> 7, r = row & 127;
  const int kcsub = lane >> 3;
  const int G = (lane & 7) >> 1;
  const int Gs = G ^ ((r >> 2) & 3);
  const int bphys = (Gs << 3) | ((lane & 1) * 4);

  float et = 0.f, ep = 0.f, sv = 0.f;
  #pragma unroll
  for (int j = 0; j < 4; j++) {
    float t_[4] = {tv[j].x, tv[j].y, tv[j].z, tv[j].w};
    float p_[4] = {pv[j].x, pv[j].y, pv[j].z, pv[j].w};
    uint32_t tpack = 0, ppack = 0;
    tpack = __builtin_amdgcn_cvt_pk_fp8_f32(t_[0] * rnt, t_[1] * rnt, tpack, false);
    tpack = __builtin_amdgcn_cvt_pk_fp8_f32(t_[2] * rnt, t_[3] * rnt, tpack, true);
    ppack = __builtin_amdgcn_cvt_pk_fp8_f32(p_[0] * rnp, p_[1] * rnp, ppack, false);
    ppack = __builtin_amdgcn_cvt_pk_fp8_f32(p_[2] * rnp, p_[3] * rnp, ppack, true);
    size_t off = ((size_t)(P * 32 + j * 8 + kcsub)) * 4096 + r * 32 + bphys;
    *(uint32_t*)(tn + off) = tpack;
    *(uint32_t*)(pn + off) = ppack;
    #pragma unroll
    for (int k = 0; k < 4; k++) {
      float e = __expf(t_[k] - mx_t);
      et += e; sv += e * (t_[k] - p_[k]);
      ep += __expf(p_[k] - mx_p);
    }
  }
  #pragma unroll
  for (int o = 32; o > 0; o >>= 1) {
    et += __shfl_xor(et, o);
    ep += __shfl_xor(ep, o);
    sv += __shfl_xor(sv, o);
  }
  if (lane == 0)
    rowkl[row] = sv / et - (mx_t - mx_p + __logf(et) - __logf(ep));
}

// ---------------- upper-triangle Gram tiles: 8-wave blocks, 3-buf depth-2 pipeline ----------------
// 528 blocks x 512 threads (8 waves: wr in {0,1} x wc in {0..3}); wave tile 64x32-dual.
// LDS: 3 x 16KB circular -> 48KB/block -> 3 blocks/CU -> 24 waves/CU, all 528 co-resident.
__global__ __launch_bounds__(512, 6) void gram_kernel(const uint8_t* __restrict__ tn,
                                                      const uint8_t* __restrict__ pn,
                                                      float* __restrict__ rowstats) {
  __shared__ __align__(16) uint8_t smem[3 * 16384];
  const int tid = threadIdx.x;
  const int wid = tid >> 6, lane = tid & 63;
  const int g = lane >> 4, lr = lane & 15;
  const int wr = wid >> 2, wc = wid & 3;

  // bijective XCD swizzle (528 % 8 == 0), then triangular decode
  int bid = blockIdx.x;
  int swz = (bid & 7) * (NTRI / 8) + (bid >> 3);
  int rb = 0, rem = swz;
  while (rem >= NPANEL - rb) { rem -= NPANEL - rb; rb++; }
  int cc = rb + rem;
  const int rowbase = rb * PANEL, colbase = cc * PANEL;

  // staging: 1024 16B-slots per buffer; 512 threads -> 2 per thread, fully coalesced
  const int matq = tid >> 8, inner = tid & 255;
  const uint8_t* srcp[2];
  uint32_t dsto[2];
  srcp[0] = (matq ? pn : tn) + (size_t)rb * PANBYTES + inner * 16;  // A panel
  srcp[1] = (matq ? pn : tn) + (size_t)cc * PANBYTES + inner * 16;  // B panel
  dsto[0] = (uint32_t)(matq * 4096 + inner * 16);
  dsto[1] = (uint32_t)(8192 + matq * 4096 + inner * 16);
  auto stage = [&](int buf, int kc) {
    #pragma unroll
    for (int i = 0; i < 2; i++)
      __builtin_amdgcn_global_load_lds(
          (const __attribute__((address_space(1))) void*)(srcp[i] + kc * 4096),
          (__attribute__((address_space(3))) void*)(smem + buf * 16384 + dsto[i]), 16, 0, 0);
  };

  f32x4 acc[4][2][2];  // [rt][ct][mat]
  #pragma unroll
  for (int rt = 0; rt < 4; rt++)
    #pragma unroll
    for (int ct = 0; ct < 2; ct++)
      #pragma unroll
      for (int m = 0; m < 2; m++)
        acc[rt][ct][m] = (f32x4){0.f, 0.f, 0.f, 0.f};

  auto body = [&](int bufidx) {
    const uint8_t* sa = smem + bufidx * 16384;
    long a[4][2];
    #pragma unroll
    for (int rt = 0; rt < 4; rt++) {
      int row = wr * 64 + rt * 16 + lr;
      int sw = (row >> 2) & 3;
      #pragma unroll
      for (int m = 0; m < 2; m++)
        a[rt][m] = *(const long*)(sa + m * 4096 + row * 32 + ((g ^ sw) << 3));
    }
    #pragma unroll
    for (int ct = 0; ct < 2; ct++) {
      int col = wc * 32 + ct * 16 + lr;
      int sw = (col >> 2) & 3;
      #pragma unroll
      for (int m = 0; m < 2; m++) {
        long b = *(const long*)(sa + 8192 + m * 4096 + col * 32 + ((g ^ sw) << 3));
        #pragma unroll
        for (int rt = 0; rt < 4; rt++)
          acc[rt][ct][m] =
              __builtin_amdgcn_mfma_f32_16x16x32_fp8_fp8(a[rt][m], b, acc[rt][ct][m], 0, 0, 0);
      }
    }
  };

  // prologue: depth-2 (4 vmem ops/wave outstanding)
  stage(0, 0); stage(1, 1);

  // steady state: wait vmcnt(2) -> stage(k) landed, stage(k+1) in flight
  #pragma unroll 3
  for (int k = 0; k < NITER - 2; k++) {
    asm volatile("s_waitcnt vmcnt(2)" ::: "memory");
    __builtin_amdgcn_s_barrier();
    stage((k + 2) % 3, k + 2);
    body(k % 3);
  }
  asm volatile("s_waitcnt vmcnt(2)" ::: "memory");
  __builtin_amdgcn_s_barrier();
  body((NITER - 2) % 3);
  asm volatile("s_waitcnt vmcnt(0)" ::: "memory");
  __builtin_amdgcn_s_barrier();
  body((NITER - 1) % 3);

  // ---- epilogue: fixed-max (m=1) stats; plain sums + spread atomics ----
  // C/D layout: row = tile + g*4 + r, col = tile + lr
  #pragma unroll
  for (int rt = 0; rt < 4; rt++) {
    #pragma unroll
    for (int r = 0; r < 4; r++) {
      float e1 = 0.f, e2 = 0.f, sl = 0.f;
      #pragma unroll
      for (int ct = 0; ct < 2; ct++) {
        float s1 = acc[rt][ct][0][r], s2 = acc[rt][ct][1][r];
        float p = __expf(s1 - 1.0f);
        e1 += p; sl += p * (s1 - s2);
        e2 += __expf(s2 - 1.0f);
      }
      #pragma unroll
      for (int mk = 1; mk < 16; mk <<= 1) {
        e1 += __shfl_xor(e1, mk);
        e2 += __shfl_xor(e2, mk);
        sl += __shfl_xor(sl, mk);
      }
      if (lr == 0) {
        int row = rowbase + wr * 64 + rt * 16 + g * 4 + r;
        atomicAdd(&rowstats[row * 3 + 0], e1);
        atomicAdd(&rowstats[row * 3 + 1], e2);
        atomicAdd(&rowstats[row * 3 + 2], sl);
      }
    }
  }
  if (rb != cc) {  // transpose contribution for off-diagonal tiles
    #pragma unroll
    for (int ct = 0; ct < 2; ct++) {
      float e1 = 0.f, e2 = 0.f, sl = 0.f;
      #pragma unroll
      for (int rt = 0; rt < 4; rt++)
        #pragma unroll
        for (int r = 0; r < 4; r++) {
          float s1 = acc[rt][ct][0][r], s2 = acc[rt][ct][1][r];
          float p = __expf(s1 - 1.0f);
          e1 += p; sl += p * (s1 - s2);
          e2 += __expf(s2 - 1.0f);
        }
      e1 += __shfl_xor(e1, 16); e2 += __shfl_xor(e2, 16); sl += __shfl_xor(sl, 16);
      e1 += __shfl_xor(e1, 32); e2 += __shfl_xor(e2, 32); sl += __shfl_xor(sl, 32);
      if (g == 0) {
        int col = colbase + wc * 32 + ct * 16 + lr;
        atomicAdd(&rowstats[col * 3 + 0], e1);
        atomicAdd(&rowstats[col * 3 + 1], e2);
        atomicAdd(&rowstats[col * 3 + 2], sl);
      }
    }
  }
}

// ---------------- single-block finalize: row KLs + prep row term -> mean ----------------
__global__ __launch_bounds__(1024) void finalize_kernel(const float* __restrict__ rowstats,
                                                        const float* __restrict__ rowkl,
                                                        float* __restrict__ out) {
  __shared__ float buf[16];
  float s = 0.f;
  for (int r = threadIdx.x; r < N; r += 1024) {
    float e1 = rowstats[r * 3 + 0];
    float e2 = rowstats[r * 3 + 1];
    float sl = rowstats[r * 3 + 2];
    s += sl / e1 - (__logf(e1) - __logf(e2)) + rowkl[r];
  }
  #pragma unroll
  for (int o = 32; o > 0; o >>= 1) s += __shfl_xor(s, o);
  if ((threadIdx.x & 63) == 0) buf[threadIdx.x >> 6] = s;
  __syncthreads();
  if (threadIdx.x == 0) {
    float t = 0.f;
    #pragma unroll
    for (int i = 0; i < 16; i++) t += buf[i];
    out[0] = t * (1.0f / (float)N);
  }
}

// ---------------- launch ----------------
extern "C" void kernel_launch(void* const* d_in, const int* in_sizes, int n_in,
                              void* d_out, int out_size, void* d_ws, size_t ws_size,
                              hipStream_t stream) {
  const float* tgt = (const float*)d_in[0];
  const float* prd = (const float*)d_in[1];
  float* out = (float*)d_out;
  char* ws = (char*)d_ws;
  // ws layout: tn 4MB (blocked fp8) | pn 4MB | rowstats N*3 f32 | rowkl N f32
  uint8_t* tn = (uint8_t*)ws;
  uint8_t* pn = (uint8_t*)(ws + 4194304);
  float* rowstats = (float*)(ws + 8388608);
  float* rowkl = rowstats + N * 3;

  zero_kernel<<<(N * 3 + 255) / 256, 256, 0, stream>>>(rowstats);
  prep_kernel<<<N / 4, 256, 0, stream>>>(tgt, prd, tn, pn, rowkl);
  gram_kernel<<<NTRI, 512, 0, stream>>>(tn, pn, rowstats);
  finalize_kernel<<<1, 1024, 0, stream>>>(rowstats, rowkl, out);
}

// Round 7
// 183.075 us; speedup vs baseline: 1.5351x; 1.5351x over previous
//
#include <hip/hip_runtime.h>
#include <hip/hip_bf16.h>
#include <math.h>

#define N 4096
#define D 1024
#define PANEL 128
#define NPANEL 32                         // N / PANEL
#define NTRI (NPANEL * (NPANEL + 1) / 2)  // 528 upper-triangle tiles
#define BK 32
#define NITER (D / BK)                    // 32 K-iters
#define PANBYTES 131072                   // one panel, one matrix: 32 kc * 4096 B

typedef float f32x4 __attribute__((ext_vector_type(4)));

// Blocked fp8 layout, per matrix (verified):
//   off(row, kc, b) = ((row>>7)*32 + kc)*4096 + (row&127)*32 + b_phys
//   b_phys: 8B-group swizzle  b_phys = ((G ^ ((r>>2)&3))<<3) | (b&7),  G = b>>3

// ---------------- zero rowstats (N*3) ----------------
__global__ void zero_kernel(float* p) {
  int i = blockIdx.x * 256 + threadIdx.x;
  if (i < N * 3) p[i] = 0.0f;
}

// ---------------- prep: wave-per-row normalize -> blocked fp8, fused row-KL ----------------
__global__ __launch_bounds__(256) void prep_kernel(const float* __restrict__ tgt,
                                                   const float* __restrict__ prd,
                                                   uint8_t* __restrict__ tn,
                                                   uint8_t* __restrict__ pn,
                                                   float* __restrict__ rowkl) {
  const int wid = threadIdx.x >> 6, lane = threadIdx.x & 63;
  const int row = blockIdx.x * 4 + wid;
  const float* tr = tgt + (size_t)row * D;
  const float* pr = prd + (size_t)row * D;
  float4 tv[4], pv[4];
  #pragma unroll
  for (int j = 0; j < 4; j++) {
    tv[j] = ((const float4*)tr)[j * 64 + lane];
    pv[j] = ((const float4*)pr)[j * 64 + lane];
  }
  float ss_t = 0.f, ss_p = 0.f, mx_t = -1e30f, mx_p = -1e30f;
  #pragma unroll
  for (int j = 0; j < 4; j++) {
    float t_[4] = {tv[j].x, tv[j].y, tv[j].z, tv[j].w};
    float p_[4] = {pv[j].x, pv[j].y, pv[j].z, pv[j].w};
    #pragma unroll
    for (int k = 0; k < 4; k++) {
      ss_t += t_[k] * t_[k]; ss_p += p_[k] * p_[k];
      mx_t = fmaxf(mx_t, t_[k]); mx_p = fmaxf(mx_p, p_[k]);
    }
  }
  #pragma unroll
  for (int o = 32; o > 0; o >>= 1) {
    ss_t += __shfl_xor(ss_t, o);
    ss_p += __shfl_xor(ss_p, o);
    mx_t = fmaxf(mx_t, __shfl_xor(mx_t, o));
    mx_p = fmaxf(mx_p, __shfl_xor(mx_p, o));
  }
  float rnt = 1.0f / fmaxf(sqrtf(ss_t), 1e-8f);
  float rnp = 1.0f / fmaxf(sqrtf(ss_p), 1e-8f);

  const int P = row >> 7, r = row & 127;
  const int kcsub = lane >> 3;
  const int G = (lane & 7) >> 1;
  const int Gs = G ^ ((r >> 2) & 3);
  const int bphys = (Gs << 3) | ((lane & 1) * 4);

  float et = 0.f, ep = 0.f, sv = 0.f;
  #pragma unroll
  for (int j = 0; j < 4; j++) {
    float t_[4] = {tv[j].x, tv[j].y, tv[j].z, tv[j].w};
    float p_[4] = {pv[j].x, pv[j].y, pv[j].z, pv[j].w};
    uint32_t tpack = 0, ppack = 0;
    tpack = __builtin_amdgcn_cvt_pk_fp8_f32(t_[0] * rnt, t_[1] * rnt, tpack, false);
    tpack = __builtin_amdgcn_cvt_pk_fp8_f32(t_[2] * rnt, t_[3] * rnt, tpack, true);
    ppack = __builtin_amdgcn_cvt_pk_fp8_f32(p_[0] * rnp, p_[1] * rnp, ppack, false);
    ppack = __builtin_amdgcn_cvt_pk_fp8_f32(p_[2] * rnp, p_[3] * rnp, ppack, true);
    size_t off = ((size_t)(P * 32 + j * 8 + kcsub)) * 4096 + r * 32 + bphys;
    *(uint32_t*)(tn + off) = tpack;
    *(uint32_t*)(pn + off) = ppack;
    #pragma unroll
    for (int k = 0; k < 4; k++) {
      float e = __expf(t_[k] - mx_t);
      et += e; sv += e * (t_[k] - p_[k]);
      ep += __expf(p_[k] - mx_p);
    }
  }
  #pragma unroll
  for (int o = 32; o > 0; o >>= 1) {
    et += __shfl_xor(et, o);
    ep += __shfl_xor(ep, o);
    sv += __shfl_xor(sv, o);
  }
  if (lane == 0)
    rowkl[row] = sv / et - (mx_t - mx_p + __logf(et) - __logf(ep));
}

// ---------------- upper-triangle Gram tiles: 8-wave blocks, 3-buf depth-2 pipeline ----------------
// 528 blocks x 512 threads (8 waves: wr in {0,1} x wc in {0..3}); wave tile 64x32-dual.
// LDS: 3 x 16KB. __launch_bounds__(512,4): 128 unified regs/wave -> no spill,
// 2 blocks/CU = 16 waves/CU (4 waves/SIMD).
__global__ __launch_bounds__(512, 4) void gram_kernel(const uint8_t* __restrict__ tn,
                                                      const uint8_t* __restrict__ pn,
                                                      float* __restrict__ rowstats) {
  __shared__ __align__(16) uint8_t smem[3 * 16384];
  const int tid = threadIdx.x;
  const int wid = tid >> 6, lane = tid & 63;
  const int g = lane >> 4, lr = lane & 15;
  const int wr = wid >> 2, wc = wid & 3;

  // bijective XCD swizzle (528 % 8 == 0), then triangular decode
  int bid = blockIdx.x;
  int swz = (bid & 7) * (NTRI / 8) + (bid >> 3);
  int rb = 0, rem = swz;
  while (rem >= NPANEL - rb) { rem -= NPANEL - rb; rb++; }
  int cc = rb + rem;
  const int rowbase = rb * PANEL, colbase = cc * PANEL;

  // staging: 1024 16B-slots per buffer; 512 threads -> 2 per thread, fully coalesced
  const int matq = tid >> 8, inner = tid & 255;
  const uint8_t* srcp[2];
  uint32_t dsto[2];
  srcp[0] = (matq ? pn : tn) + (size_t)rb * PANBYTES + inner * 16;  // A panel
  srcp[1] = (matq ? pn : tn) + (size_t)cc * PANBYTES + inner * 16;  // B panel
  dsto[0] = (uint32_t)(matq * 4096 + inner * 16);
  dsto[1] = (uint32_t)(8192 + matq * 4096 + inner * 16);
  auto stage = [&](int buf, int kc) {
    #pragma unroll
    for (int i = 0; i < 2; i++)
      __builtin_amdgcn_global_load_lds(
          (const __attribute__((address_space(1))) void*)(srcp[i] + kc * 4096),
          (__attribute__((address_space(3))) void*)(smem + buf * 16384 + dsto[i]), 16, 0, 0);
  };

  f32x4 acc[4][2][2];  // [rt][ct][mat] -> 64 regs/lane
  #pragma unroll
  for (int rt = 0; rt < 4; rt++)
    #pragma unroll
    for (int ct = 0; ct < 2; ct++)
      #pragma unroll
      for (int m = 0; m < 2; m++)
        acc[rt][ct][m] = (f32x4){0.f, 0.f, 0.f, 0.f};

  auto body = [&](int bufidx) {
    const uint8_t* sa = smem + bufidx * 16384;
    long a[4][2];
    #pragma unroll
    for (int rt = 0; rt < 4; rt++) {
      int row = wr * 64 + rt * 16 + lr;
      int sw = (row >> 2) & 3;
      #pragma unroll
      for (int m = 0; m < 2; m++)
        a[rt][m] = *(const long*)(sa + m * 4096 + row * 32 + ((g ^ sw) << 3));
    }
    #pragma unroll
    for (int ct = 0; ct < 2; ct++) {
      int col = wc * 32 + ct * 16 + lr;
      int sw = (col >> 2) & 3;
      #pragma unroll
      for (int m = 0; m < 2; m++) {
        long b = *(const long*)(sa + 8192 + m * 4096 + col * 32 + ((g ^ sw) << 3));
        #pragma unroll
        for (int rt = 0; rt < 4; rt++)
          acc[rt][ct][m] =
              __builtin_amdgcn_mfma_f32_16x16x32_fp8_fp8(a[rt][m], b, acc[rt][ct][m], 0, 0, 0);
      }
    }
  };

  // prologue: depth-2 (4 vmem ops/wave outstanding)
  stage(0, 0); stage(1, 1);

  // steady state: wait vmcnt(2) -> stage(k) landed, stage(k+1) in flight
  #pragma unroll 3
  for (int k = 0; k < NITER - 2; k++) {
    asm volatile("s_waitcnt vmcnt(2)" ::: "memory");
    __builtin_amdgcn_s_barrier();
    stage((k + 2) % 3, k + 2);
    body(k % 3);
  }
  asm volatile("s_waitcnt vmcnt(2)" ::: "memory");
  __builtin_amdgcn_s_barrier();
  body((NITER - 2) % 3);
  asm volatile("s_waitcnt vmcnt(0)" ::: "memory");
  __builtin_amdgcn_s_barrier();
  body((NITER - 1) % 3);

  // ---- epilogue: fixed-max (m=1) stats; plain sums + spread atomics ----
  // C/D layout: row = tile + g*4 + r, col = tile + lr
  #pragma unroll
  for (int rt = 0; rt < 4; rt++) {
    #pragma unroll
    for (int r = 0; r < 4; r++) {
      float e1 = 0.f, e2 = 0.f, sl = 0.f;
      #pragma unroll
      for (int ct = 0; ct < 2; ct++) {
        float s1 = acc[rt][ct][0][r], s2 = acc[rt][ct][1][r];
        float p = __expf(s1 - 1.0f);
        e1 += p; sl += p * (s1 - s2);
        e2 += __expf(s2 - 1.0f);
      }
      #pragma unroll
      for (int mk = 1; mk < 16; mk <<= 1) {
        e1 += __shfl_xor(e1, mk);
        e2 += __shfl_xor(e2, mk);
        sl += __shfl_xor(sl, mk);
      }
      if (lr == 0) {
        int row = rowbase + wr * 64 + rt * 16 + g * 4 + r;
        atomicAdd(&rowstats[row * 3 + 0], e1);
        atomicAdd(&rowstats[row * 3 + 1], e2);
        atomicAdd(&rowstats[row * 3 + 2], sl);
      }
    }
  }
  if (rb != cc) {  // transpose contribution for off-diagonal tiles
    #pragma unroll
    for (int ct = 0; ct < 2; ct++) {
      float e1 = 0.f, e2 = 0.f, sl = 0.f;
      #pragma unroll
      for (int rt = 0; rt < 4; rt++)
        #pragma unroll
        for (int r = 0; r < 4; r++) {
          float s1 = acc[rt][ct][0][r], s2 = acc[rt][ct][1][r];
          float p = __expf(s1 - 1.0f);
          e1 += p; sl += p * (s1 - s2);
          e2 += __expf(s2 - 1.0f);
        }
      e1 += __shfl_xor(e1, 16); e2 += __shfl_xor(e2, 16); sl += __shfl_xor(sl, 16);
      e1 += __shfl_xor(e1, 32); e2 += __shfl_xor(e2, 32); sl += __shfl_xor(sl, 32);
      if (g == 0) {
        int col = colbase + wc * 32 + ct * 16 + lr;
        atomicAdd(&rowstats[col * 3 + 0], e1);
        atomicAdd(&rowstats[col * 3 + 1], e2);
        atomicAdd(&rowstats[col * 3 + 2], sl);
      }
    }
  }
}

// ---------------- single-block finalize: row KLs + prep row term -> mean ----------------
__global__ __launch_bounds__(1024) void finalize_kernel(const float* __restrict__ rowstats,
                                                        const float* __restrict__ rowkl,
                                                        float* __restrict__ out) {
  __shared__ float buf[16];
  float s = 0.f;
  for (int r = threadIdx.x; r < N; r += 1024) {
    float e1 = rowstats[r * 3 + 0];
    float e2 = rowstats[r * 3 + 1];
    float sl = rowstats[r * 3 + 2];
    s += sl / e1 - (__logf(e1) - __logf(e2)) + rowkl[r];
  }
  #pragma unroll
  for (int o = 32; o > 0; o >>= 1) s += __shfl_xor(s, o);
  if ((threadIdx.x & 63) == 0) buf[threadIdx.x >> 6] = s;
  __syncthreads();
  if (threadIdx.x == 0) {
    float t = 0.f;
    #pragma unroll
    for (int i = 0; i < 16; i++) t += buf[i];
    out[0] = t * (1.0f / (float)N);
  }
}

// ---------------- launch ----------------
extern "C" void kernel_launch(void* const* d_in, const int* in_sizes, int n_in,
                              void* d_out, int out_size, void* d_ws, size_t ws_size,
                              hipStream_t stream) {
  const float* tgt = (const float*)d_in[0];
  const float* prd = (const float*)d_in[1];
  float* out = (float*)d_out;
  char* ws = (char*)d_ws;
  // ws layout: tn 4MB (blocked fp8) | pn 4MB | rowstats N*3 f32 | rowkl N f32
  uint8_t* tn = (uint8_t*)ws;
  uint8_t* pn = (uint8_t*)(ws + 4194304);
  float* rowstats = (float*)(ws + 8388608);
  float* rowkl = rowstats + N * 3;

  zero_kernel<<<(N * 3 + 255) / 256, 256, 0, stream>>>(rowstats);
  prep_kernel<<<N / 4, 256, 0, stream>>>(tgt, prd, tn, pn, rowkl);
  gram_kernel<<<NTRI, 512, 0, stream>>>(tn, pn, rowstats);
  finalize_kernel<<<1, 1024, 0, stream>>>(rowstats, rowkl, out);
}

// Round 8
// 92.288 us; speedup vs baseline: 3.0452x; 1.9837x over previous
//
#include <hip/hip_runtime.h>
#include <hip/hip_bf16.h>
#include <math.h>

#define N 4096
#define D 1024
#define PANEL 128
#define NPANEL 32                         // N / PANEL
#define NTRI (NPANEL * (NPANEL + 1) / 2)  // 528 upper-triangle tiles
#define BK 64
#define NITER (D / BK)                    // 16 K-iters
#define PANBYTES 131072                   // one panel, one matrix: 32 kc * 4096 B

typedef float f32x4 __attribute__((ext_vector_type(4)));

// Blocked fp8 layout, per matrix (verified r5-r7):
//   off(row, kc, b) = ((row>>7)*32 + kc)*4096 + (row&127)*32 + b_phys
//   b_phys: 8B-group swizzle  b_phys = ((G ^ ((r>>2)&3))<<3) | (b&7),  G = b>>3

// ---------------- zero rowstats (N*3) ----------------
__global__ void zero_kernel(float* p) {
  int i = blockIdx.x * 256 + threadIdx.x;
  if (i < N * 3) p[i] = 0.0f;
}

// ---------------- prep: wave-per-row normalize -> blocked fp8, fused row-KL ----------------
__global__ __launch_bounds__(256) void prep_kernel(const float* __restrict__ tgt,
                                                   const float* __restrict__ prd,
                                                   uint8_t* __restrict__ tn,
                                                   uint8_t* __restrict__ pn,
                                                   float* __restrict__ rowkl) {
  const int wid = threadIdx.x >> 6, lane = threadIdx.x & 63;
  const int row = blockIdx.x * 4 + wid;
  const float* tr = tgt + (size_t)row * D;
  const float* pr = prd + (size_t)row * D;
  float4 tv[4], pv[4];
  #pragma unroll
  for (int j = 0; j < 4; j++) {
    tv[j] = ((const float4*)tr)[j * 64 + lane];
    pv[j] = ((const float4*)pr)[j * 64 + lane];
  }
  float ss_t = 0.f, ss_p = 0.f, mx_t = -1e30f, mx_p = -1e30f;
  #pragma unroll
  for (int j = 0; j < 4; j++) {
    float t_[4] = {tv[j].x, tv[j].y, tv[j].z, tv[j].w};
    float p_[4] = {pv[j].x, pv[j].y, pv[j].z, pv[j].w};
    #pragma unroll
    for (int k = 0; k < 4; k++) {
      ss_t += t_[k] * t_[k]; ss_p += p_[k] * p_[k];
      mx_t = fmaxf(mx_t, t_[k]); mx_p = fmaxf(mx_p, p_[k]);
    }
  }
  #pragma unroll
  for (int o = 32; o > 0; o >>= 1) {
    ss_t += __shfl_xor(ss_t, o);
    ss_p += __shfl_xor(ss_p, o);
    mx_t = fmaxf(mx_t, __shfl_xor(mx_t, o));
    mx_p = fmaxf(mx_p, __shfl_xor(mx_p, o));
  }
  float rnt = 1.0f / fmaxf(sqrtf(ss_t), 1e-8f);
  float rnp = 1.0f / fmaxf(sqrtf(ss_p), 1e-8f);

  const int P = row >> 7, r = row & 127;
  const int kcsub = lane >> 3;
  const int G = (lane & 7) >> 1;
  const int Gs = G ^ ((r >> 2) & 3);
  const int bphys = (Gs << 3) | ((lane & 1) * 4);

  float et = 0.f, ep = 0.f, sv = 0.f;
  #pragma unroll
  for (int j = 0; j < 4; j++) {
    float t_[4] = {tv[j].x, tv[j].y, tv[j].z, tv[j].w};
    float p_[4] = {pv[j].x, pv[j].y, pv[j].z, pv[j].w};
    uint32_t tpack = 0, ppack = 0;
    tpack = __builtin_amdgcn_cvt_pk_fp8_f32(t_[0] * rnt, t_[1] * rnt, tpack, false);
    tpack = __builtin_amdgcn_cvt_pk_fp8_f32(t_[2] * rnt, t_[3] * rnt, tpack, true);
    ppack = __builtin_amdgcn_cvt_pk_fp8_f32(p_[0] * rnp, p_[1] * rnp, ppack, false);
    ppack = __builtin_amdgcn_cvt_pk_fp8_f32(p_[2] * rnp, p_[3] * rnp, ppack, true);
    size_t off = ((size_t)(P * 32 + j * 8 + kcsub)) * 4096 + r * 32 + bphys;
    *(uint32_t*)(tn + off) = tpack;
    *(uint32_t*)(pn + off) = ppack;
    #pragma unroll
    for (int k = 0; k < 4; k++) {
      float e = __expf(t_[k] - mx_t);
      et += e; sv += e * (t_[k] - p_[k]);
      ep += __expf(p_[k] - mx_p);
    }
  }
  #pragma unroll
  for (int o = 32; o > 0; o >>= 1) {
    et += __shfl_xor(et, o);
    ep += __shfl_xor(ep, o);
    sv += __shfl_xor(sv, o);
  }
  if (lane == 0)
    rowkl[row] = sv / et - (mx_t - mx_p + __logf(et) - __logf(ep));
}

// ---------------- upper-triangle Gram tiles: BK=64 dbuf + L2 supertiles ----------------
// 528 blocks x 256 threads (4 waves, 2x2; wave tile 64x64-dual, acc 128 regs).
// LDS: 2 x 32KB double buffer. One vmcnt(0)+barrier per K-iter; stage(k+1)
// issued before body(k) so its flight is covered by ~310cy of MFMA.
// Supertile remap: 4x4-panel supertiles (2MB working set <= 4MB L2/XCD);
// XCD x runs blocks p in [x*66,(x+1)*66) walking supertiles in canonical order.
__global__ __launch_bounds__(256, 2) void gram_kernel(const uint8_t* __restrict__ tn,
                                                      const uint8_t* __restrict__ pn,
                                                      float* __restrict__ rowstats) {
  __shared__ __align__(16) uint8_t smem[2 * 32768];
  const int tid = threadIdx.x;
  const int wid = tid >> 6, lane = tid & 63;
  const int g = lane >> 4, lr = lane & 15;
  const int wr = wid >> 1, wc = wid & 1;

  // ---- supertile decode: p -> (supertile R,C) -> (panel rb, cc) ----
  int p = (blockIdx.x & 7) * (NTRI / 8) + (blockIdx.x >> 3);  // [0,528)
  int rem = p, R = 0, C = 0, sz = 0;
  bool found = false;
  for (R = 0; R < 8 && !found; R++) {
    for (C = R; C < 8; C++) {
      sz = (R == C) ? 10 : 16;
      if (rem < sz) { found = true; break; }
      rem -= sz;
    }
  }
  R--;  // loop increments past
  int pr, pc;
  if (R == C) {  // 4x4 upper triangle incl diagonal: 10 entries
    pr = 0;
    while (rem >= 4 - pr) { rem -= 4 - pr; pr++; }
    pc = pr + rem;
  } else {
    pr = rem >> 2; pc = rem & 3;
  }
  const int rb = R * 4 + pr, cc = C * 4 + pc;
  const int rowbase = rb * PANEL, colbase = cc * PANEL;

  // ---- staging: 2048 16B-slots per 32KB buffer -> 8 per thread ----
  // LDS buffer layout: [region 0..3 = At,Ap,Bt,Bp][chunk 0..1][row 0..127][32B]
  const uint8_t* mats[2] = {tn, pn};
  const uint8_t* srcp[8];
  #pragma unroll
  for (int i = 0; i < 8; i++) {
    int L = i * 256 + tid;           // [0,2048)
    int region = L >> 9;             // 0:At 1:Ap 2:Bt 3:Bp
    int isB = region >> 1, mat = region & 1;
    int q = L & 511;                 // 8KB region: [chunk][256 slots]
    int chunk = q >> 8, inner = q & 255;
    srcp[i] = mats[mat] + (size_t)(isB ? cc : rb) * PANBYTES + chunk * 4096 + inner * 16;
  }
  auto stage = [&](int buf, int k) {
    #pragma unroll
    for (int i = 0; i < 8; i++)
      __builtin_amdgcn_global_load_lds(
          (const __attribute__((address_space(1))) void*)(srcp[i] + k * 8192),
          (__attribute__((address_space(3))) void*)(smem + buf * 32768 + i * 4096 + tid * 16),
          16, 0, 0);
  };

  f32x4 acc[4][4][2];  // [rt][ct][mat] -> 128 regs/lane
  #pragma unroll
  for (int rt = 0; rt < 4; rt++)
    #pragma unroll
    for (int ct = 0; ct < 4; ct++)
      #pragma unroll
      for (int m = 0; m < 2; m++)
        acc[rt][ct][m] = (f32x4){0.f, 0.f, 0.f, 0.f};

  auto body = [&](int buf) {
    const uint8_t* sa = smem + buf * 32768;
    #pragma unroll
    for (int ks = 0; ks < 2; ks++) {
      long a[4][2];
      #pragma unroll
      for (int rt = 0; rt < 4; rt++) {
        int row = wr * 64 + rt * 16 + lr;
        int sw = (row >> 2) & 3;
        #pragma unroll
        for (int m = 0; m < 2; m++)
          a[rt][m] = *(const long*)(sa + m * 8192 + ks * 4096 + row * 32 + ((g ^ sw) << 3));
      }
      #pragma unroll
      for (int ct = 0; ct < 4; ct++) {
        int col = wc * 64 + ct * 16 + lr;
        int sw = (col >> 2) & 3;
        #pragma unroll
        for (int m = 0; m < 2; m++) {
          long b = *(const long*)(sa + 16384 + m * 8192 + ks * 4096 + col * 32 + ((g ^ sw) << 3));
          #pragma unroll
          for (int rt = 0; rt < 4; rt++)
            acc[rt][ct][m] =
                __builtin_amdgcn_mfma_f32_16x16x32_fp8_fp8(a[rt][m], b, acc[rt][ct][m], 0, 0, 0);
        }
      }
    }
  };

  stage(0, 0);
  #pragma unroll 2
  for (int k = 0; k < NITER; k++) {
    asm volatile("s_waitcnt vmcnt(0)" ::: "memory");
    __builtin_amdgcn_s_barrier();
    if (k < NITER - 1) stage((k + 1) & 1, k + 1);  // flight covered by body(k)
    body(k & 1);
  }

  // ---- epilogue: fixed-max (m=1) stats; plain sums + spread atomics ----
  // C/D layout: row = tile + g*4 + r, col = tile + lr
  #pragma unroll
  for (int rt = 0; rt < 4; rt++) {
    #pragma unroll
    for (int r = 0; r < 4; r++) {
      float e1 = 0.f, e2 = 0.f, sl = 0.f;
      #pragma unroll
      for (int ct = 0; ct < 4; ct++) {
        float s1 = acc[rt][ct][0][r], s2 = acc[rt][ct][1][r];
        float pw = __expf(s1 - 1.0f);
        e1 += pw; sl += pw * (s1 - s2);
        e2 += __expf(s2 - 1.0f);
      }
      #pragma unroll
      for (int mk = 1; mk < 16; mk <<= 1) {
        e1 += __shfl_xor(e1, mk);
        e2 += __shfl_xor(e2, mk);
        sl += __shfl_xor(sl, mk);
      }
      if (lr == 0) {
        int row = rowbase + wr * 64 + rt * 16 + g * 4 + r;
        atomicAdd(&rowstats[row * 3 + 0], e1);
        atomicAdd(&rowstats[row * 3 + 1], e2);
        atomicAdd(&rowstats[row * 3 + 2], sl);
      }
    }
  }
  if (rb != cc) {  // transpose contribution for off-diagonal tiles
    #pragma unroll
    for (int ct = 0; ct < 4; ct++) {
      float e1 = 0.f, e2 = 0.f, sl = 0.f;
      #pragma unroll
      for (int rt = 0; rt < 4; rt++)
        #pragma unroll
        for (int r = 0; r < 4; r++) {
          float s1 = acc[rt][ct][0][r], s2 = acc[rt][ct][1][r];
          float pw = __expf(s1 - 1.0f);
          e1 += pw; sl += pw * (s1 - s2);
          e2 += __expf(s2 - 1.0f);
        }
      e1 += __shfl_xor(e1, 16); e2 += __shfl_xor(e2, 16); sl += __shfl_xor(sl, 16);
      e1 += __shfl_xor(e1, 32); e2 += __shfl_xor(e2, 32); sl += __shfl_xor(sl, 32);
      if (g == 0) {
        int col = colbase + wc * 64 + ct * 16 + lr;
        atomicAdd(&rowstats[col * 3 + 0], e1);
        atomicAdd(&rowstats[col * 3 + 1], e2);
        atomicAdd(&rowstats[col * 3 + 2], sl);
      }
    }
  }
}

// ---------------- single-block finalize: row KLs + prep row term -> mean ----------------
__global__ __launch_bounds__(1024) void finalize_kernel(const float* __restrict__ rowstats,
                                                        const float* __restrict__ rowkl,
                                                        float* __restrict__ out) {
  __shared__ float buf[16];
  float s = 0.f;
  for (int r = threadIdx.x; r < N; r += 1024) {
    float e1 = rowstats[r * 3 + 0];
    float e2 = rowstats[r * 3 + 1];
    float sl = rowstats[r * 3 + 2];
    s += sl / e1 - (__logf(e1) - __logf(e2)) + rowkl[r];
  }
  #pragma unroll
  for (int o = 32; o > 0; o >>= 1) s += __shfl_xor(s, o);
  if ((threadIdx.x & 63) == 0) buf[threadIdx.x >> 6] = s;
  __syncthreads();
  if (threadIdx.x == 0) {
    float t = 0.f;
    #pragma unroll
    for (int i = 0; i < 16; i++) t += buf[i];
    out[0] = t * (1.0f / (float)N);
  }
}

// ---------------- launch ----------------
extern "C" void kernel_launch(void* const* d_in, const int* in_sizes, int n_in,
                              void* d_out, int out_size, void* d_ws, size_t ws_size,
                              hipStream_t stream) {
  const float* tgt = (const float*)d_in[0];
  const float* prd = (const float*)d_in[1];
  float* out = (float*)d_out;
  char* ws = (char*)d_ws;
  // ws layout: tn 4MB (blocked fp8) | pn 4MB | rowstats N*3 f32 | rowkl N f32
  uint8_t* tn = (uint8_t*)ws;
  uint8_t* pn = (uint8_t*)(ws + 4194304);
  float* rowstats = (float*)(ws + 8388608);
  float* rowkl = rowstats + N * 3;

  zero_kernel<<<(N * 3 + 255) / 256, 256, 0, stream>>>(rowstats);
  prep_kernel<<<N / 4, 256, 0, stream>>>(tgt, prd, tn, pn, rowkl);
  gram_kernel<<<NTRI, 256, 0, stream>>>(tn, pn, rowstats);
  finalize_kernel<<<1, 1024, 0, stream>>>(rowstats, rowkl, out);
}